// Round 5
// baseline (36123.062 us; speedup 1.0000x reference)
//
#include <hip/hip_runtime.h>
#include <stdint.h>

#define S_LEN 8192
#define DIM   2048
#define W2    4096   // W row length = 2*DIM

typedef __attribute__((ext_vector_type(8))) __bf16 bf16x8;
typedef __attribute__((ext_vector_type(4))) float  floatx4;
typedef unsigned long long u64;
typedef unsigned int       u32;

// ---------------------------------------------------------------------------
// Init: 2 x 1024 packed tags. Entry k covers rows {2k,2k+1}:
// hi32 = bf16(s[2k]) | bf16(s[2k+1])<<16, lo32 = step tag.
// s_0 = -1.0 -> bf16 0xBF80. Tag 0 in both buffers (buf1 blocks until step 2).
// ---------------------------------------------------------------------------
__global__ void init_pairs(u64* __restrict__ pairs) {
  int i = blockIdx.x * 256 + threadIdx.x;
  if (i < 2048) pairs[i] = 0xBF80BF80ull << 32;
}

// ---------------------------------------------------------------------------
// GEMM: C[m][n] = sum_k A[m][k] * W[n*4096 + 2048 + k] + b[n]   (unchanged)
// ---------------------------------------------------------------------------
__device__ inline bf16x8 pack_bf8(float4 a, float4 b) {
  bf16x8 h;
  h[0] = (__bf16)a.x; h[1] = (__bf16)a.y; h[2] = (__bf16)a.z; h[3] = (__bf16)a.w;
  h[4] = (__bf16)b.x; h[5] = (__bf16)b.y; h[6] = (__bf16)b.z; h[7] = (__bf16)b.w;
  return h;
}

__global__ __launch_bounds__(256) void gemm_ctx(const float* __restrict__ A,
                                                const float* __restrict__ W,
                                                const float* __restrict__ bias,
                                                float* __restrict__ C) {
  __shared__ __bf16 As[64][72];
  __shared__ __bf16 Bs[64][72];
  const int tid  = threadIdx.x;
  const int m0   = blockIdx.y * 64;
  const int n0   = blockIdx.x * 64;
  const int w    = tid >> 6;
  const int lane = tid & 63;
  const int wm   = w >> 1, wn = w & 1;
  const int r    = tid >> 2;
  const int seg  = tid & 3;

  floatx4 acc[2][2] = {};

  for (int k0 = 0; k0 < DIM; k0 += 64) {
    {
      const float* pa = A + (size_t)(m0 + r) * DIM + k0 + seg * 16;
      const float* pb = W + (size_t)(n0 + r) * W2 + DIM + k0 + seg * 16;
      float4 a0 = ((const float4*)pa)[0], a1 = ((const float4*)pa)[1];
      float4 a2 = ((const float4*)pa)[2], a3 = ((const float4*)pa)[3];
      float4 b0 = ((const float4*)pb)[0], b1 = ((const float4*)pb)[1];
      float4 b2 = ((const float4*)pb)[2], b3 = ((const float4*)pb)[3];
      *(bf16x8*)&As[r][seg * 16]     = pack_bf8(a0, a1);
      *(bf16x8*)&As[r][seg * 16 + 8] = pack_bf8(a2, a3);
      *(bf16x8*)&Bs[r][seg * 16]     = pack_bf8(b0, b1);
      *(bf16x8*)&Bs[r][seg * 16 + 8] = pack_bf8(b2, b3);
    }
    __syncthreads();
    #pragma unroll
    for (int kk = 0; kk < 64; kk += 32) {
      const int ks = kk + (lane >> 4) * 8;
      bf16x8 af[2], bfr[2];
      af[0]  = *(const bf16x8*)&As[32 * wm +      (lane & 15)][ks];
      af[1]  = *(const bf16x8*)&As[32 * wm + 16 + (lane & 15)][ks];
      bfr[0] = *(const bf16x8*)&Bs[32 * wn +      (lane & 15)][ks];
      bfr[1] = *(const bf16x8*)&Bs[32 * wn + 16 + (lane & 15)][ks];
      #pragma unroll
      for (int im = 0; im < 2; ++im)
        #pragma unroll
        for (int in = 0; in < 2; ++in)
          acc[im][in] = __builtin_amdgcn_mfma_f32_16x16x32_bf16(
              af[im], bfr[in], acc[im][in], 0, 0, 0);
    }
    __syncthreads();
  }

  #pragma unroll
  for (int in = 0; in < 2; ++in) {
    const int col = n0 + 32 * wn + 16 * in + (lane & 15);
    const float bv = bias[col];
    #pragma unroll
    for (int im = 0; im < 2; ++im) {
      const int rbase = m0 + 32 * wm + 16 * im + (lane >> 4) * 4;
      #pragma unroll
      for (int q = 0; q < 4; ++q)
        C[(size_t)(rbase + q) * DIM + col] = acc[im][in][q] + bv;
    }
  }
}

// ---------------------------------------------------------------------------
// Persistent recurrence v5: 128 WGs x 512 threads (8 waves), 1 WG/CU.
// WG k owns rows [16k,16k+16); wave w owns rows (i0+2w, i0+2w+1); lane l owns
// cols [32l,32l+32).
// v5: W slab lives in LDS (128 KB fp32, XOR-swizzled cols) — R3/R4 proved the
// register allocator rematerializes/spills any big VGPR slab. State crosses
// WGs as packed bf16 pairs (u64 = 2xbf16 | tag), halving poll fan-out.
// ---------------------------------------------------------------------------
__global__ __launch_bounds__(512, 1) void recur(const float* __restrict__ W,
                                                const float* __restrict__ ce,
                                                float* __restrict__ out,
                                                u64* __restrict__ tags) {
  __shared__ __align__(16) float Wl[16 * 2048];  // 128 KB
  __shared__ __align__(16) float st[DIM];        // 8 KB
  const int tid = threadIdx.x;
  const int w = tid >> 6, l = tid & 63;
  const int blk = blockIdx.x;
  const int i0 = blk * 16;

  // ---- one-time: W slab -> LDS, cols XOR-swizzled (phys = c ^ ((c>>5&7)<<2))
  #pragma unroll
  for (int j = 0; j < 16; ++j) {
    const int f   = j * 512 + tid;       // float4 index within 16x2048 slab
    const int row = f >> 9;              // 512 float4 per row
    const int lc  = (f & 511) << 2;      // logical col
    const int pc  = lc ^ (((lc >> 5) & 7) << 2);
    float4 v = *(const float4*)(W + (size_t)(i0 + row) * W2 + lc);
    *(float4*)&Wl[row * 2048 + pc] = v;
  }

  const int g0 = i0 + 2 * w;             // this wave's global row pair
  const bool owner = (l == 0);
  float hcm0 = -3.0e38f, hcm1 = -3.0e38f;
  float s0_last = 0.f, s1_last = 0.f;
  u64* b0 = tags;
  u64* b1 = tags + 1024;
  const int base  = tid * 2;             // 512 threads x 2 tags = 1024
  const int slot4 = (4 * tid) ^ (((tid >> 3) & 7) << 2);
  const int mytag = blk * 8 + w;

  // step-1 operands
  float2 cev = {0.f, 0.f}, cxv = {0.f, 0.f};
  if (owner) {
    cev = *(const float2*)&ce[g0];
    cxv = *(const float2*)&out[g0];
  }
  __syncthreads();  // Wl ready

  for (int t = 1; t <= S_LEN; ++t) {
    // ---- poll: 1024 tags of s_{t-1} in buf[(t-1)&1] ----
    u64* src = ((t - 1) & 1) ? b1 : b0;
    const u32 want = (u32)(t - 1);
    u64 v0 = __hip_atomic_load(&src[base], __ATOMIC_RELAXED,
                               __HIP_MEMORY_SCOPE_AGENT);
    u64 v1 = __hip_atomic_load(&src[base + 1], __ATOMIC_RELAXED,
                               __HIP_MEMORY_SCOPE_AGENT);
    for (;;) {
      bool bad0 = ((u32)v0 != want);
      bool bad1 = ((u32)v1 != want);
      if (!(bad0 || bad1)) break;
      if (bad0) v0 = __hip_atomic_load(&src[base], __ATOMIC_RELAXED,
                                       __HIP_MEMORY_SCOPE_AGENT);
      if (bad1) v1 = __hip_atomic_load(&src[base + 1], __ATOMIC_RELAXED,
                                       __HIP_MEMORY_SCOPE_AGENT);
    }

    // ---- issue NEXT step's stream loads (resolve during next poll) ----
    float2 ncev = {0.f, 0.f}, ncxv = {0.f, 0.f};
    if (owner && t < S_LEN) {
      ncev = *(const float2*)&ce[(size_t)t * DIM + g0];
      ncxv = *(const float2*)&out[(size_t)t * DIM + g0];
    }

    __syncthreads();  // prior-iteration LDS reads complete
    {
      const u32 h0 = (u32)(v0 >> 32), h1 = (u32)(v1 >> 32);
      float4 sv4;
      sv4.x = __uint_as_float(h0 << 16);          // bf16 -> fp32
      sv4.y = __uint_as_float(h0 & 0xffff0000u);
      sv4.z = __uint_as_float(h1 << 16);
      sv4.w = __uint_as_float(h1 & 0xffff0000u);
      *(float4*)&st[slot4] = sv4;
    }
    __syncthreads();

    // ---- matvec: rows 2w, 2w+1 from LDS-resident W ----
    const float* Wr0 = &Wl[(2 * w) * 2048];
    const float* Wr1 = &Wl[(2 * w + 1) * 2048];
    float a0 = 0.f, a1 = 0.f;
    #pragma unroll
    for (int jj = 0; jj < 8; ++jj) {
      const int off = 32 * l + 4 * (jj ^ (l & 7));
      const float4 sv = *(const float4*)&st[off];
      const float4 wa = *(const float4*)&Wr0[off];
      const float4 wb = *(const float4*)&Wr1[off];
      a0 = fmaf(wa.x, sv.x, a0); a0 = fmaf(wa.y, sv.y, a0);
      a0 = fmaf(wa.z, sv.z, a0); a0 = fmaf(wa.w, sv.w, a0);
      a1 = fmaf(wb.x, sv.x, a1); a1 = fmaf(wb.y, sv.y, a1);
      a1 = fmaf(wb.z, sv.z, a1); a1 = fmaf(wb.w, sv.w, a1);
    }

    // ---- 64-lane butterfly reduce ----
    #pragma unroll
    for (int m = 1; m < 64; m <<= 1) {
      a0 += __shfl_xor(a0, m, 64);
      a1 += __shfl_xor(a1, m, 64);
    }

    if (owner) {
      const float y0 = a0 + cxv.x;
      const float y1 = a1 + cxv.y;
      hcm0 = fmaxf(hcm0, cev.x);
      hcm1 = fmaxf(hcm1, cev.y);
      const float s0 = hcm0 / (1.0f + __expf(-y0));
      const float s1 = hcm1 / (1.0f + __expf(-y1));
      // tag store FIRST — global critical path
      __bf16 hb0 = (__bf16)s0, hb1 = (__bf16)s1;
      const u32 hi = (u32)*(unsigned short*)&hb0 |
                     ((u32)*(unsigned short*)&hb1 << 16);
      u64* dst = (t & 1) ? b1 : b0;
      const u64 pk = ((u64)hi << 32) | (u64)(u32)t;
      __hip_atomic_store(&dst[mytag], pk, __ATOMIC_RELAXED,
                         __HIP_MEMORY_SCOPE_AGENT);
      float2 sv2; sv2.x = s0; sv2.y = s1;
      *(float2*)&out[(size_t)(t - 1) * DIM + g0] = sv2;
      s0_last = s0; s1_last = s1;
    }
    cev = ncev;
    cxv = ncxv;
  }

  if (owner) {
    float2 sv2; sv2.x = s0_last; sv2.y = s1_last;
    *(float2*)&out[(size_t)S_LEN * DIM + g0] = sv2;
  }
}

// ---------------------------------------------------------------------------
extern "C" void kernel_launch(void* const* d_in, const int* in_sizes, int n_in,
                              void* d_out, int out_size, void* d_ws, size_t ws_size,
                              hipStream_t stream) {
  const float* ce = (const float*)d_in[0];
  const float* W  = (const float*)d_in[1];
  const float* b  = (const float*)d_in[2];
  float* out = (float*)d_out;
  u64* pairs = (u64*)d_ws;   // 2 * 1024 * 8B = 16 KB

  hipLaunchKernelGGL(init_pairs, dim3(8), dim3(256), 0, stream, pairs);
  hipLaunchKernelGGL(gemm_ctx, dim3(DIM / 64, S_LEN / 64), dim3(256), 0, stream,
                     ce, W, b, out);
  hipLaunchKernelGGL(recur, dim3(128), dim3(512), 0, stream, W, ce, out, pairs);
}